// Round 3
// baseline (776.728 us; speedup 1.0000x reference)
//
#include <hip/hip_runtime.h>

// ---------- bf16 helpers (raw ushort representation) ----------
__device__ __forceinline__ float bf2f(unsigned short u) {
    union { unsigned int i; float f; } v;
    v.i = ((unsigned int)u) << 16;
    return v.f;
}
__device__ __forceinline__ unsigned short f2bf(float f) {
    union { float f; unsigned int i; } v;
    v.f = f;
    unsigned int r = (v.i + 0x7fffu + ((v.i >> 16) & 1u)) >> 16;
    return (unsigned short)r;
}

typedef __attribute__((ext_vector_type(8))) short short8;
typedef __attribute__((ext_vector_type(4))) float floatx4;

#define GLOBAL_AS __attribute__((address_space(1)))
#define LDS_AS __attribute__((address_space(3)))

static constexpr int Bdim = 8;
static constexpr int Tdim = 2048;
static constexpr int Cdim = 1024;
static constexpr int Edim = 4096;
static constexpr int Mdim = Bdim * Tdim;  // 16384

// ---------- weight transpose + cast: src fp32 (K x N) -> dst bf16 (N x K) ----------
__global__ __launch_bounds__(256) void transpose_f2b(
    const float* __restrict__ src, unsigned short* __restrict__ dst, int K, int N) {
    __shared__ float tile[32][33];
    int n0 = blockIdx.x * 32;
    int k0 = blockIdx.y * 32;
    int tx = threadIdx.x & 31;
    int ty = threadIdx.x >> 5;  // 0..7
#pragma unroll
    for (int i = 0; i < 32; i += 8)
        tile[ty + i][tx] = src[(size_t)(k0 + ty + i) * N + n0 + tx];
    __syncthreads();
#pragma unroll
    for (int i = 0; i < 32; i += 8)
        dst[(size_t)(n0 + ty + i) * K + k0 + tx] = f2bf(tile[tx][ty + i]);
}

// ---------- rmsnorm1 inverse-RMS only: rinv[row] = rsqrt(mean(x^2)+eps) ----------
__global__ __launch_bounds__(256) void rms_inv_kernel(
    const float* __restrict__ x, float* __restrict__ rinv) {
    int row = blockIdx.x;
    int tid = threadIdx.x;
    float4 v = ((const float4*)(x + (size_t)row * Cdim))[tid];
    float s = v.x * v.x + v.y * v.y + v.z * v.z + v.w * v.w;
#pragma unroll
    for (int o = 32; o > 0; o >>= 1) s += __shfl_down(s, o, 64);
    __shared__ float ps[4];
    if ((tid & 63) == 0) ps[tid >> 6] = s;
    __syncthreads();
    if (tid == 0) {
        float tot = ps[0] + ps[1] + ps[2] + ps[3];
        rinv[row] = rsqrtf(tot * (1.0f / (float)Cdim) + 1e-6f);
    }
}

// ---------- cumsum phase A: per-chunk sums of y = x*rinv*w. 1024 blocks ----------
__global__ __launch_bounds__(256) void chunk_sums(
    const float* __restrict__ x, const float* __restrict__ rinv,
    const float* __restrict__ w, float* __restrict__ P) {
    int idx = blockIdx.x;
    int cb = idx & 3;
    int k = (idx >> 2) & 31;
    int b = idx >> 7;
    int c = cb * 256 + threadIdx.x;
    float wc = w[c];
    const float* base = x + ((size_t)b * Tdim + k * 64) * Cdim + c;
    const float* rbase = rinv + (size_t)b * Tdim + k * 64;
    float s = 0.f;
#pragma unroll 8
    for (int t = 0; t < 64; t++) s += base[(size_t)t * Cdim] * rbase[t];
    P[((size_t)b * 32 + k) * Cdim + c] = s * wc;
}

// ---------- cumsum phase B: exclusive scan of 32 chunk sums per (b,c) chain ----------
__global__ __launch_bounds__(256) void chunk_scan(float* __restrict__ P) {
    int g = blockIdx.x * 256 + threadIdx.x;  // 0..8191
    int b = g >> 10;
    int c = g & 1023;
    float* p = P + (size_t)b * 32 * Cdim + c;
    float run = 0.f;
#pragma unroll
    for (int k = 0; k < 32; k++) {
        float v = p[(size_t)k * Cdim];
        p[(size_t)k * Cdim] = run;
        run += v;
    }
}

// ---------- cumsum phase C: rescan, divide by triangular scaler, emit bf16 state ----------
__global__ __launch_bounds__(256) void cumsum_state(
    const float* __restrict__ x, const float* __restrict__ rinv,
    const float* __restrict__ w, const float* __restrict__ P,
    unsigned short* __restrict__ state) {
    int idx = blockIdx.x;
    int cb = idx & 3;
    int k = (idx >> 2) & 31;
    int b = idx >> 7;
    int c = cb * 256 + threadIdx.x;
    float wc = w[c];
    float acc = P[((size_t)b * 32 + k) * Cdim + c];
    const float* base = x + ((size_t)b * Tdim + k * 64) * Cdim + c;
    const float* rbase = rinv + (size_t)b * Tdim + k * 64;
    unsigned short* sbase = state + ((size_t)b * Tdim + k * 64) * Cdim + c;
#pragma unroll 4
    for (int t = 0; t < 64; t++) {
        acc += base[(size_t)t * Cdim] * rbase[t] * wc;
        int tt = k * 64 + t;
        float inv = 2.0f / ((float)(tt + 1) * (float)(tt + 2));
        sbase[(size_t)t * Cdim] = f2bf(acc * inv);
    }
}

// ---------- rmsnorm2: fp32 in -> bf16 out (GEMM A operand) ----------
__global__ __launch_bounds__(256) void rmsnorm_f2b(
    const float* __restrict__ x, const float* __restrict__ w,
    unsigned short* __restrict__ y) {
    int row = blockIdx.x;
    int tid = threadIdx.x;
    float4 v = ((const float4*)(x + (size_t)row * Cdim))[tid];
    float s = v.x * v.x + v.y * v.y + v.z * v.z + v.w * v.w;
#pragma unroll
    for (int o = 32; o > 0; o >>= 1) s += __shfl_down(s, o, 64);
    __shared__ float ps[4];
    if ((tid & 63) == 0) ps[tid >> 6] = s;
    __syncthreads();
    float tot = ps[0] + ps[1] + ps[2] + ps[3];
    float r = rsqrtf(tot * (1.0f / (float)Cdim) + 1e-6f);
    float4 w4 = ((const float4*)w)[tid];
    ushort4 o;
    o.x = f2bf(v.x * r * w4.x);
    o.y = f2bf(v.y * r * w4.y);
    o.z = f2bf(v.z * r * w4.z);
    o.w = f2bf(v.w * r * w4.w);
    ((ushort4*)(y + (size_t)row * Cdim))[tid] = o;
}

// ---------- bf16 MFMA GEMM: 256x256, BK=64, 8-phase READ-AHEAD pipeline ----------
// C(MxN) = A(MxK) @ BT^T. 512 threads = 8 waves (2M x 4N), per-wave 128x64, acc[8][4].
// 2 LDS buffers (buf t&1 = K-tile t). ONE barrier per phase, placed between
// {reads+stages+WAR-waits} and {MFMA}. Fragment reads for phase p are issued in
// phase p-1 (group-entry phase issues 12 = this-phase 8 + next 4), so the LDS pipe
// drains phase p+1's reads WHILE phase p's MFMA runs (compiler auto-lgkm protects
// MFMA operands at fine grain; DS ops complete in issue order; phase boundaries are
// pinned by asm-volatile memory clobbers, so counted waits are exact).
// Phase map for iteration j (tile0=2j/buf0, tile1=2j+1/buf1):
//  ph0: read F0{A[0-3]k0,B k0}+F1{A[4-7]k0} (12); stage A1-u0,u1 | MFMA acc[0-3] k0
//  ph1: read F2{A[0-3]k1,B k1} (8);           stage A1-u2,u3     | MFMA acc[4-7] k0
//  ph2: read F3{A[4-7]k1} (4); lgkm(4) PRE-bar (B-k1 reads drained -> ph3 B-restage
//       WAR-safe)                                                | MFMA acc[0-3] k1
//  ph3: stage B2-u0,u1; lgkm(0) PRE-bar (A reads drained -> ph4 A-restage safe);
//       vmcnt(2) gate (B1[prev ph7]+A1[ph0,1] landed; B2-u0,u1 in flight)
//                                                                | MFMA acc[4-7] k1
//  ph4-7: mirror on buf1; ph4 stages B2-u2,u3+A2-u0,u1; ph5 A2-u2,u3;
//       ph7 stages B3-u0..u3, gate vmcnt(4) (B2+A2 landed, B3 in flight).
// Every staged load gets >=2 phases in flight before its gate.
template <int EPI>
__global__ __launch_bounds__(512, 2) void gemm8(
    const unsigned short* __restrict__ A, const unsigned short* __restrict__ BT,
    const float* __restrict__ bias, const float* __restrict__ extra,
    void* __restrict__ Coutv, int N, int K) {
    __shared__ __attribute__((aligned(16))) unsigned short As[2][256 * 64];
    __shared__ __attribute__((aligned(16))) unsigned short Bs[2][256 * 64];

    int tid = threadIdx.x;
    int nbn = N >> 8;
    int id = blockIdx.x;
    int nwg = gridDim.x;
    if ((nwg & 7) == 0) id = (id & 7) * (nwg >> 3) + (id >> 3);
    int bn = id % nbn;
    int bm = id / nbn;

    int lane = tid & 63;
    int w = tid >> 6;     // 0..7
    int wm = w >> 2;      // 0..1 : rows wm*128 .. +127
    int wn = w & 3;       // 0..3 : cols wn*64 .. +63
    int lrow = lane & 15;
    int l4 = lane >> 4;   // 0..3
    int swz = lrow & 7;
    int wmB = wm * 128, wnB = wn * 64;

    const unsigned short* Abase = A + (size_t)bm * 256 * K;
    const unsigned short* Bbase = BT + (size_t)bn * 256 * K;

    // staging: unit u = 64 rows x 64 cols (8KB) = 1 global_load_lds per thread.
    int sr = tid >> 3;
    int col8 = (tid & 7) ^ (sr & 7);

#define STAGE_A(sb, u, k0)                                                               \
    __builtin_amdgcn_global_load_lds(                                                    \
        (const GLOBAL_AS void*)(Abase + (size_t)((u) * 64 + sr) * K + (k0) + col8 * 8),  \
        (LDS_AS void*)(As[sb] + (u) * 4096 + tid * 8), 16, 0, 0)
#define STAGE_B(sb, u, k0)                                                               \
    __builtin_amdgcn_global_load_lds(                                                    \
        (const GLOBAL_AS void*)(Bbase + (size_t)((u) * 64 + sr) * K + (k0) + col8 * 8),  \
        (LDS_AS void*)(Bs[sb] + (u) * 4096 + tid * 8), 16, 0, 0)

#define LDA(cb, i, ks)                                                                   \
    (*(const short8*)(As[cb] + (wmB + (i) * 16 + lrow) * 64 + ((((ks) * 4 + l4) ^ swz) << 3)))
#define LDB(cb, jj, ks)                                                                  \
    (*(const short8*)(Bs[cb] + (wnB + (jj) * 16 + lrow) * 64 + ((((ks) * 4 + l4) ^ swz) << 3)))

#define BAR __builtin_amdgcn_s_barrier()
#define LGK(n) asm volatile("s_waitcnt lgkmcnt(" #n ")" ::: "memory")
#define MM(R, AV, BV)                                                                    \
    do {                                                                                 \
        __builtin_amdgcn_s_setprio(1);                                                   \
        _Pragma("unroll") for (int i_ = 0; i_ < 4; i_++)                                 \
            _Pragma("unroll") for (int q_ = 0; q_ < 4; q_++)                             \
                acc[(R) + i_][q_] = __builtin_amdgcn_mfma_f32_16x16x32_bf16(             \
                    AV[i_], BV[q_], acc[(R) + i_][q_], 0, 0, 0);                         \
        __builtin_amdgcn_s_setprio(0);                                                   \
    } while (0)

    floatx4 acc[8][4] = {};
    int nt = K >> 6;
    int nIter = nt >> 1;

    // prologue: A0,B0 full; B1 full. vmcnt(4): tile0 landed, B1 (4 loads) in flight.
    STAGE_A(0, 0, 0); STAGE_A(0, 1, 0); STAGE_A(0, 2, 0); STAGE_A(0, 3, 0);
    STAGE_B(0, 0, 0); STAGE_B(0, 1, 0); STAGE_B(0, 2, 0); STAGE_B(0, 3, 0);
    STAGE_B(1, 0, 64); STAGE_B(1, 1, 64); STAGE_B(1, 2, 64); STAGE_B(1, 3, 64);
    asm volatile("s_waitcnt vmcnt(4)" ::: "memory");
    BAR;

    for (int j = 0; j < nIter; ++j) {
        int k1 = (2 * j + 1) << 6;
        int k2 = (2 * j + 2) << 6;
        int k3 = (2 * j + 3) << 6;
        bool nl = (j + 1 < nIter);

        short8 a0[4], a1[4], a2[4], a3[4], b0[4], b1[4];

        // ---- ph0: batch-read F0+F1 (12); stage A1-lo ----
#pragma unroll
        for (int i = 0; i < 4; i++) a0[i] = LDA(0, i, 0);
#pragma unroll
        for (int q = 0; q < 4; q++) b0[q] = LDB(0, q, 0);
#pragma unroll
        for (int i = 0; i < 4; i++) a1[i] = LDA(0, 4 + i, 0);
        STAGE_A(1, 0, k1); STAGE_A(1, 1, k1);
        BAR;
        MM(0, a0, b0);

        // ---- ph1: read F2 (8); stage A1-hi ----
#pragma unroll
        for (int i = 0; i < 4; i++) a2[i] = LDA(0, i, 1);
#pragma unroll
        for (int q = 0; q < 4; q++) b1[q] = LDB(0, q, 1);
        STAGE_A(1, 2, k1); STAGE_A(1, 3, k1);
        BAR;
        MM(4, a1, b0);

        // ---- ph2: read F3 (4); lgkm(4) pre-barrier (F2 drained: old-B WAR) ----
#pragma unroll
        for (int i = 0; i < 4; i++) a3[i] = LDA(0, 4 + i, 1);
        LGK(4);
        BAR;
        MM(0, a2, b1);

        // ---- ph3: stage B2-lo; lgkm(0) (old-A WAR); vmcnt gate; MFMA ----
        if (nl) { STAGE_B(0, 0, k2); STAGE_B(0, 1, k2); }
        LGK(0);
        if (nl) asm volatile("s_waitcnt vmcnt(2)" ::: "memory");
        else    asm volatile("s_waitcnt vmcnt(0)" ::: "memory");
        BAR;
        MM(4, a3, b1);

        // ---- ph4: batch-read F0'+F1' from buf1 (12); stage B2-hi + A2-lo ----
#pragma unroll
        for (int i = 0; i < 4; i++) a0[i] = LDA(1, i, 0);
#pragma unroll
        for (int q = 0; q < 4; q++) b0[q] = LDB(1, q, 0);
#pragma unroll
        for (int i = 0; i < 4; i++) a1[i] = LDA(1, 4 + i, 0);
        if (nl) { STAGE_B(0, 2, k2); STAGE_B(0, 3, k2); STAGE_A(0, 0, k2); STAGE_A(0, 1, k2); }
        BAR;
        MM(0, a0, b0);

        // ---- ph5: read F2' (8); stage A2-hi ----
#pragma unroll
        for (int i = 0; i < 4; i++) a2[i] = LDA(1, i, 1);
#pragma unroll
        for (int q = 0; q < 4; q++) b1[q] = LDB(1, q, 1);
        if (nl) { STAGE_A(0, 2, k2); STAGE_A(0, 3, k2); }
        BAR;
        MM(4, a1, b0);

        // ---- ph6: read F3' (4); lgkm(4) pre-barrier ----
#pragma unroll
        for (int i = 0; i < 4; i++) a3[i] = LDA(1, 4 + i, 1);
        LGK(4);
        BAR;
        MM(0, a2, b1);

        // ---- ph7: stage B3 (4 units); lgkm(0); vmcnt gate; MFMA ----
        if (nl) { STAGE_B(1, 0, k3); STAGE_B(1, 1, k3); STAGE_B(1, 2, k3); STAGE_B(1, 3, k3); }
        LGK(0);
        if (nl) asm volatile("s_waitcnt vmcnt(4)" ::: "memory");
        else    asm volatile("s_waitcnt vmcnt(0)" ::: "memory");
        BAR;
        MM(4, a3, b1);
    }
#undef STAGE_A
#undef STAGE_B
#undef LDA
#undef LDB
#undef BAR
#undef LGK
#undef MM

    // epilogue: C/D layout col=lane&15, row=(lane>>4)*4+reg
    int crow = l4 << 2;
    int ccol = lane & 15;
#pragma unroll
    for (int i = 0; i < 8; i++) {
#pragma unroll
        for (int q = 0; q < 4; q++) {
            size_t gm = (size_t)bm * 256 + wmB + i * 16 + crow;
            size_t gn = (size_t)bn * 256 + wnB + q * 16 + ccol;
            float bsv = bias[gn];
#pragma unroll
            for (int r = 0; r < 4; r++) {
                float v = acc[i][q][r] + bsv;
                size_t off = (gm + r) * (size_t)N + gn;
                if (EPI == 0) {
                    float g = 1.f / (1.f + __expf(-v));
                    ((float*)Coutv)[off] = g * extra[off];
                } else if (EPI == 1) {
                    ((unsigned short*)Coutv)[off] = f2bf(v > 0.f ? v : 0.f);
                } else {
                    ((float*)Coutv)[off] = v + extra[off];
                }
            }
        }
    }
}

// ---------- launch ----------
extern "C" void kernel_launch(void* const* d_in, const int* in_sizes, int n_in,
                              void* d_out, int out_size, void* d_ws, size_t ws_size,
                              hipStream_t stream) {
    const float* x   = (const float*)d_in[0];  // (B,T,C) fp32
    const float* n1w = (const float*)d_in[1];  // (C)
    const float* w1  = (const float*)d_in[2];  // (C,C)
    const float* b1  = (const float*)d_in[3];  // (C)
    const float* n2w = (const float*)d_in[4];  // (C)
    const float* w21 = (const float*)d_in[5];  // (C,E)
    const float* b21 = (const float*)d_in[6];  // (E)
    const float* w22 = (const float*)d_in[7];  // (E,C)
    const float* b22 = (const float*)d_in[8];  // (C)
    float* out = (float*)d_out;                // (B,T,C) fp32

    char* ws = (char*)d_ws;
    const size_t MB = 1024ull * 1024ull;
    unsigned short* state = (unsigned short*)(ws);            // 32MB bf16; reused as hnorm
    unsigned short* w1T   = (unsigned short*)(ws + 32 * MB);  // 2MB  (C x C) bf16
    unsigned short* w21T  = (unsigned short*)(ws + 34 * MB);  // 8MB  (E x C) bf16
    unsigned short* w22T  = (unsigned short*)(ws + 42 * MB);  // 8MB  (C x E) bf16
    float* P              = (float*)(ws + 50 * MB);           // 1MB
    float* rinv           = (float*)(ws + 51 * MB);           // 64KB
    unsigned short* h     = (unsigned short*)(ws + 52 * MB);  // up to 128MB bf16 (sliced)
    float* out1 = out;  // gate*x lives in d_out (fp32); G3 reads then overwrites per-element

    // pick M-slice size for the h buffer based on available workspace
    int slice_rows = Mdim;  // 16384 -> h=128MB (total 180MB); halve until it fits
    while (52 * MB + (size_t)slice_rows * Edim * 2 > ws_size && slice_rows > 1024)
        slice_rows >>= 1;

    // weights -> bf16 (N x K)
    transpose_f2b<<<dim3(Cdim / 32, Cdim / 32), 256, 0, stream>>>(w1, w1T, Cdim, Cdim);
    transpose_f2b<<<dim3(Edim / 32, Cdim / 32), 256, 0, stream>>>(w21, w21T, Cdim, Edim);
    transpose_f2b<<<dim3(Cdim / 32, Edim / 32), 256, 0, stream>>>(w22, w22T, Edim, Cdim);

    // rmsnorm1 scale factors
    rms_inv_kernel<<<Mdim, 256, 0, stream>>>(x, rinv);

    // chunked cumsum of x*rinv*n1w over T, with triangular scaler -> bf16 state
    chunk_sums<<<1024, 256, 0, stream>>>(x, rinv, n1w, P);
    chunk_scan<<<32, 256, 0, stream>>>(P);
    cumsum_state<<<1024, 256, 0, stream>>>(x, rinv, n1w, P, state);

    // G1: out1 = sigmoid(state @ w1 + b1) * x   (fp32 out into d_out)
    gemm8<0><<<dim3((Mdim / 256) * (Cdim / 256)), 512, 0, stream>>>(
        state, w1T, b1, x, out1, Cdim, Cdim);

    // rmsnorm2(out1) -> bf16 hnorm (reuse state buffer)
    rmsnorm_f2b<<<Mdim, 256, 0, stream>>>(out1, n2w, state);

    // G2/G3 sliced over M to bound the h buffer
    for (int m0 = 0; m0 < Mdim; m0 += slice_rows) {
        gemm8<1><<<dim3((slice_rows / 256) * (Edim / 256)), 512, 0, stream>>>(
            state + (size_t)m0 * Cdim, w21T, b21, nullptr, h, Edim, Cdim);
        gemm8<2><<<dim3((slice_rows / 256) * (Cdim / 256)), 512, 0, stream>>>(
            h, w22T, b22, out1 + (size_t)m0 * Cdim, out + (size_t)m0 * Cdim,
            Cdim, Edim);
    }
}

// Round 4
// 591.666 us; speedup vs baseline: 1.3128x; 1.3128x over previous
//
#include <hip/hip_runtime.h>

// ---------- bf16 helpers (raw ushort representation) ----------
__device__ __forceinline__ float bf2f(unsigned short u) {
    union { unsigned int i; float f; } v;
    v.i = ((unsigned int)u) << 16;
    return v.f;
}
__device__ __forceinline__ unsigned short f2bf(float f) {
    union { float f; unsigned int i; } v;
    v.f = f;
    unsigned int r = (v.i + 0x7fffu + ((v.i >> 16) & 1u)) >> 16;
    return (unsigned short)r;
}

typedef __attribute__((ext_vector_type(8))) short short8;
typedef __attribute__((ext_vector_type(4))) float floatx4;

#define GLOBAL_AS __attribute__((address_space(1)))
#define LDS_AS __attribute__((address_space(3)))

static constexpr int Bdim = 8;
static constexpr int Tdim = 2048;
static constexpr int Cdim = 1024;
static constexpr int Edim = 4096;
static constexpr int Mdim = Bdim * Tdim;  // 16384

// ---------- weight transpose + cast: src fp32 (K x N) -> dst bf16 (N x K) ----------
__global__ __launch_bounds__(256) void transpose_f2b(
    const float* __restrict__ src, unsigned short* __restrict__ dst, int K, int N) {
    __shared__ float tile[32][33];
    int n0 = blockIdx.x * 32;
    int k0 = blockIdx.y * 32;
    int tx = threadIdx.x & 31;
    int ty = threadIdx.x >> 5;  // 0..7
#pragma unroll
    for (int i = 0; i < 32; i += 8)
        tile[ty + i][tx] = src[(size_t)(k0 + ty + i) * N + n0 + tx];
    __syncthreads();
#pragma unroll
    for (int i = 0; i < 32; i += 8)
        dst[(size_t)(n0 + ty + i) * K + k0 + tx] = f2bf(tile[tx][ty + i]);
}

// ---------- rmsnorm1 inverse-RMS only: rinv[row] = rsqrt(mean(x^2)+eps) ----------
__global__ __launch_bounds__(256) void rms_inv_kernel(
    const float* __restrict__ x, float* __restrict__ rinv) {
    int row = blockIdx.x;
    int tid = threadIdx.x;
    float4 v = ((const float4*)(x + (size_t)row * Cdim))[tid];
    float s = v.x * v.x + v.y * v.y + v.z * v.z + v.w * v.w;
#pragma unroll
    for (int o = 32; o > 0; o >>= 1) s += __shfl_down(s, o, 64);
    __shared__ float ps[4];
    if ((tid & 63) == 0) ps[tid >> 6] = s;
    __syncthreads();
    if (tid == 0) {
        float tot = ps[0] + ps[1] + ps[2] + ps[3];
        rinv[row] = rsqrtf(tot * (1.0f / (float)Cdim) + 1e-6f);
    }
}

// ---------- cumsum phase A: per-chunk sums of y = x*rinv*w. 1024 blocks ----------
__global__ __launch_bounds__(256) void chunk_sums(
    const float* __restrict__ x, const float* __restrict__ rinv,
    const float* __restrict__ w, float* __restrict__ P) {
    int idx = blockIdx.x;
    int cb = idx & 3;
    int k = (idx >> 2) & 31;
    int b = idx >> 7;
    int c = cb * 256 + threadIdx.x;
    float wc = w[c];
    const float* base = x + ((size_t)b * Tdim + k * 64) * Cdim + c;
    const float* rbase = rinv + (size_t)b * Tdim + k * 64;
    float s = 0.f;
#pragma unroll 8
    for (int t = 0; t < 64; t++) s += base[(size_t)t * Cdim] * rbase[t];
    P[((size_t)b * 32 + k) * Cdim + c] = s * wc;
}

// ---------- cumsum phase B: exclusive scan of 32 chunk sums per (b,c) chain ----------
__global__ __launch_bounds__(256) void chunk_scan(float* __restrict__ P) {
    int g = blockIdx.x * 256 + threadIdx.x;  // 0..8191
    int b = g >> 10;
    int c = g & 1023;
    float* p = P + (size_t)b * 32 * Cdim + c;
    float run = 0.f;
#pragma unroll
    for (int k = 0; k < 32; k++) {
        float v = p[(size_t)k * Cdim];
        p[(size_t)k * Cdim] = run;
        run += v;
    }
}

// ---------- cumsum phase C: rescan, divide by triangular scaler, emit bf16 state ----------
__global__ __launch_bounds__(256) void cumsum_state(
    const float* __restrict__ x, const float* __restrict__ rinv,
    const float* __restrict__ w, const float* __restrict__ P,
    unsigned short* __restrict__ state) {
    int idx = blockIdx.x;
    int cb = idx & 3;
    int k = (idx >> 2) & 31;
    int b = idx >> 7;
    int c = cb * 256 + threadIdx.x;
    float wc = w[c];
    float acc = P[((size_t)b * 32 + k) * Cdim + c];
    const float* base = x + ((size_t)b * Tdim + k * 64) * Cdim + c;
    const float* rbase = rinv + (size_t)b * Tdim + k * 64;
    unsigned short* sbase = state + ((size_t)b * Tdim + k * 64) * Cdim + c;
#pragma unroll 4
    for (int t = 0; t < 64; t++) {
        acc += base[(size_t)t * Cdim] * rbase[t] * wc;
        int tt = k * 64 + t;
        float inv = 2.0f / ((float)(tt + 1) * (float)(tt + 2));
        sbase[(size_t)t * Cdim] = f2bf(acc * inv);
    }
}

// ---------- rmsnorm2: fp32 in -> bf16 out (GEMM A operand) ----------
__global__ __launch_bounds__(256) void rmsnorm_f2b(
    const float* __restrict__ x, const float* __restrict__ w,
    unsigned short* __restrict__ y) {
    int row = blockIdx.x;
    int tid = threadIdx.x;
    float4 v = ((const float4*)(x + (size_t)row * Cdim))[tid];
    float s = v.x * v.x + v.y * v.y + v.z * v.z + v.w * v.w;
#pragma unroll
    for (int o = 32; o > 0; o >>= 1) s += __shfl_down(s, o, 64);
    __shared__ float ps[4];
    if ((tid & 63) == 0) ps[tid >> 6] = s;
    __syncthreads();
    float tot = ps[0] + ps[1] + ps[2] + ps[3];
    float r = rsqrtf(tot * (1.0f / (float)Cdim) + 1e-6f);
    float4 w4 = ((const float4*)w)[tid];
    ushort4 o;
    o.x = f2bf(v.x * r * w4.x);
    o.y = f2bf(v.y * r * w4.y);
    o.z = f2bf(v.z * r * w4.z);
    o.w = f2bf(v.w * r * w4.w);
    ((ushort4*)(y + (size_t)row * Cdim))[tid] = o;
}

// ---------- bf16 MFMA GEMM: 256x256, BK=64, 8-phase, deep-A pipeline ----------
// C(MxN) = A(MxK) @ BT^T. 512 threads = 8 waves (2M x 4N), per-wave 128x64, acc[8][4].
// As[3] (A = streamed/HBM operand: 3 buffers, 4-7 phase staging lead) +
// Bs[2] (B = L2-resident weights: 2 buffers, 3-4 phase lead) = 160 KiB (full LDS;
// occupancy was already 1 block/CU at 128 KiB, so no loss).
// Iteration j consumes tile 2j (As[aR], Bs[0], ph0-3) and 2j+1 (As[aR+1], Bs[1], ph4-7).
// Phase = {reads; stage 2 gload_lds/thread; BAR; lgkm(0); prio1; 16 MFMA; prio0;
//          [vm gate]; BAR}. Gates sit AFTER the MFMA cluster: each gated load gains
//  the ~620-cyc MFMA window as extra lead time.
// Stagger (WAR-safe: each dest buffer's last ds_read was drained by that reader's
// lgkm(0), and a barrier separates it from the stage issue):
//   ph0/1: B(2j+1)->Bs[1]   [Bs[1] last read prev ph4-7]
//   ph2/3: A(2j+2)->As[aR+2][last held 2j-1, read prev ph4-7]
//   ph4/5: B(2j+2)->Bs[0]   [read this iter ph0-3]
//   ph6/7: A(2j+3)->As[aR]  [read this iter ph0-3]
// Gates (in-order vmcnt retirement; 12 loads outstanding at each gate):
//   ph3: vmcnt(4) drains A(2j+1)[prev ph6/7] + B(2j+1)[ph0/1] (both needed ph4);
//        leaves A(2j+2) in flight.
//   ph7: vmcnt(4) drains A(2j+2)[ph2/3] + B(2j+2)[ph4/5] (needed next ph0);
//        leaves A(2j+3) in flight.
// Every drained load is >=4 phases old. LDS XOR-swizzle slot^=(row&7) via
// pre-swizzled global source (linear gload_lds dest).
template <int EPI>
__global__ __launch_bounds__(512, 2) void gemm8(
    const unsigned short* __restrict__ A, const unsigned short* __restrict__ BT,
    const float* __restrict__ bias, const float* __restrict__ extra,
    void* __restrict__ Coutv, int N, int K) {
    __shared__ __attribute__((aligned(16))) unsigned short As[3][256 * 64];
    __shared__ __attribute__((aligned(16))) unsigned short Bs[2][256 * 64];

    int tid = threadIdx.x;
    int nbn = N >> 8;
    int id = blockIdx.x;
    int nwg = gridDim.x;
    if ((nwg & 7) == 0) id = (id & 7) * (nwg >> 3) + (id >> 3);
    int bn = id % nbn;
    int bm = id / nbn;

    int lane = tid & 63;
    int w = tid >> 6;     // 0..7
    int wm = w >> 2;      // 0..1 : rows wm*128 .. +127
    int wn = w & 3;       // 0..3 : cols wn*64 .. +63
    int lrow = lane & 15;
    int l4 = lane >> 4;   // 0..3
    int swz = lrow & 7;
    int wmB = wm * 128, wnB = wn * 64;

    const unsigned short* Abase = A + (size_t)bm * 256 * K;
    const unsigned short* Bbase = BT + (size_t)bn * 256 * K;

    // staging: unit u = 64 rows x 64 cols (8KB) = 1 global_load_lds per thread.
    int sr = tid >> 3;
    int col8 = (tid & 7) ^ (sr & 7);

#define STAGE_A(sb, u, k0)                                                               \
    __builtin_amdgcn_global_load_lds(                                                    \
        (const GLOBAL_AS void*)(Abase + (size_t)((u) * 64 + sr) * K + (k0) + col8 * 8),  \
        (LDS_AS void*)(As[sb] + (u) * 4096 + tid * 8), 16, 0, 0)
#define STAGE_B(sb, u, k0)                                                               \
    __builtin_amdgcn_global_load_lds(                                                    \
        (const GLOBAL_AS void*)(Bbase + (size_t)((u) * 64 + sr) * K + (k0) + col8 * 8),  \
        (LDS_AS void*)(Bs[sb] + (u) * 4096 + tid * 8), 16, 0, 0)

#define LDA(ptr, i, ks)                                                                  \
    (*(const short8*)((ptr) + (wmB + (i) * 16 + lrow) * 64 + ((((ks) * 4 + l4) ^ swz) << 3)))
#define LDB(cb, jj, ks)                                                                  \
    (*(const short8*)(Bs[cb] + (wnB + (jj) * 16 + lrow) * 64 + ((((ks) * 4 + l4) ^ swz) << 3)))

#define BAR __builtin_amdgcn_s_barrier()
#define LGK0 asm volatile("s_waitcnt lgkmcnt(0)" ::: "memory")
#define MM(R, AV, BV)                                                                    \
    do {                                                                                 \
        __builtin_amdgcn_s_setprio(1);                                                   \
        _Pragma("unroll") for (int i_ = 0; i_ < 4; i_++)                                 \
            _Pragma("unroll") for (int q_ = 0; q_ < 4; q_++)                             \
                acc[(R) + i_][q_] = __builtin_amdgcn_mfma_f32_16x16x32_bf16(             \
                    AV[i_], BV[q_], acc[(R) + i_][q_], 0, 0, 0);                         \
        __builtin_amdgcn_s_setprio(0);                                                   \
    } while (0)

    floatx4 acc[8][4] = {};
    int nt = K >> 6;
    int nIter = nt >> 1;

    // prologue: A(0)->As[0], B(0)->Bs[0], A(1)->As[1]. vmcnt(4): tile 0 landed,
    // A(1) (4 loads, oldest-in-queue for the j=0 ph3 gate) stays in flight.
    STAGE_A(0, 0, 0); STAGE_A(0, 1, 0); STAGE_A(0, 2, 0); STAGE_A(0, 3, 0);
    STAGE_B(0, 0, 0); STAGE_B(0, 1, 0); STAGE_B(0, 2, 0); STAGE_B(0, 3, 0);
    STAGE_A(1, 0, 64); STAGE_A(1, 1, 64); STAGE_A(1, 2, 64); STAGE_A(1, 3, 64);
    asm volatile("s_waitcnt vmcnt(4)" ::: "memory");
    BAR;

    int aR = 0;  // As index of tile 2j
    for (int j = 0; j < nIter; ++j) {
        int aNx = aR + 1; if (aNx == 3) aNx = 0;      // As index of tile 2j+1
        int aP2 = aNx + 1; if (aP2 == 3) aP2 = 0;     // As index for tile 2j+2
        const unsigned short* Ab0 = As[aR];
        const unsigned short* Ab1 = As[aNx];
        int k1 = (2 * j + 1) << 6;
        int k2 = (2 * j + 2) << 6;
        int k3 = (2 * j + 3) << 6;
        bool nl = (j + 1 < nIter);

        short8 av[4], b0[4], b1[4];

        // ---- ph0: A[0-3]k0 + B k0 (8 reads); stage B(2j+1) u0,u1 ----
#pragma unroll
        for (int i = 0; i < 4; i++) av[i] = LDA(Ab0, i, 0);
#pragma unroll
        for (int q = 0; q < 4; q++) b0[q] = LDB(0, q, 0);
        STAGE_B(1, 0, k1); STAGE_B(1, 1, k1);
        BAR; LGK0;
        MM(0, av, b0);
        BAR;

        // ---- ph1: A[4-7]k0 + B k1 (8 reads); stage B(2j+1) u2,u3 ----
#pragma unroll
        for (int i = 0; i < 4; i++) av[i] = LDA(Ab0, 4 + i, 0);
#pragma unroll
        for (int q = 0; q < 4; q++) b1[q] = LDB(0, q, 1);
        STAGE_B(1, 2, k1); STAGE_B(1, 3, k1);
        BAR; LGK0;
        MM(4, av, b0);
        BAR;

        // ---- ph2: A[0-3]k1 (4 reads); stage A(2j+2) u0,u1 ----
#pragma unroll
        for (int i = 0; i < 4; i++) av[i] = LDA(Ab0, i, 1);
        if (nl) { STAGE_A(aP2, 0, k2); STAGE_A(aP2, 1, k2); }
        BAR; LGK0;
        MM(0, av, b1);
        BAR;

        // ---- ph3: A[4-7]k1 (4 reads); stage A(2j+2) u2,u3; gate AFTER MFMA ----
#pragma unroll
        for (int i = 0; i < 4; i++) av[i] = LDA(Ab0, 4 + i, 1);
        if (nl) { STAGE_A(aP2, 2, k2); STAGE_A(aP2, 3, k2); }
        BAR; LGK0;
        MM(4, av, b1);
        if (nl) asm volatile("s_waitcnt vmcnt(4)" ::: "memory");
        else    asm volatile("s_waitcnt vmcnt(0)" ::: "memory");
        BAR;

        // ---- ph4: A'[0-3]k0 + B' k0 (8 reads); stage B(2j+2) u0,u1 ----
#pragma unroll
        for (int i = 0; i < 4; i++) av[i] = LDA(Ab1, i, 0);
#pragma unroll
        for (int q = 0; q < 4; q++) b0[q] = LDB(1, q, 0);
        if (nl) { STAGE_B(0, 0, k2); STAGE_B(0, 1, k2); }
        BAR; LGK0;
        MM(0, av, b0);
        BAR;

        // ---- ph5: A'[4-7]k0 + B' k1 (8 reads); stage B(2j+2) u2,u3 ----
#pragma unroll
        for (int i = 0; i < 4; i++) av[i] = LDA(Ab1, 4 + i, 0);
#pragma unroll
        for (int q = 0; q < 4; q++) b1[q] = LDB(1, q, 1);
        if (nl) { STAGE_B(0, 2, k2); STAGE_B(0, 3, k2); }
        BAR; LGK0;
        MM(4, av, b0);
        BAR;

        // ---- ph6: A'[0-3]k1 (4 reads); stage A(2j+3) u0,u1 ----
#pragma unroll
        for (int i = 0; i < 4; i++) av[i] = LDA(Ab1, i, 1);
        if (nl) { STAGE_A(aR, 0, k3); STAGE_A(aR, 1, k3); }
        BAR; LGK0;
        MM(0, av, b1);
        BAR;

        // ---- ph7: A'[4-7]k1 (4 reads); stage A(2j+3) u2,u3; gate AFTER MFMA ----
#pragma unroll
        for (int i = 0; i < 4; i++) av[i] = LDA(Ab1, 4 + i, 1);
        if (nl) { STAGE_A(aR, 2, k3); STAGE_A(aR, 3, k3); }
        BAR; LGK0;
        MM(4, av, b1);
        if (nl) asm volatile("s_waitcnt vmcnt(4)" ::: "memory");
        BAR;

        aR = aP2;
    }
#undef STAGE_A
#undef STAGE_B
#undef LDA
#undef LDB
#undef BAR
#undef LGK0
#undef MM

    // epilogue: C/D layout col=lane&15, row=(lane>>4)*4+reg
    int crow = l4 << 2;
    int ccol = lane & 15;
#pragma unroll
    for (int i = 0; i < 8; i++) {
#pragma unroll
        for (int q = 0; q < 4; q++) {
            size_t gm = (size_t)bm * 256 + wmB + i * 16 + crow;
            size_t gn = (size_t)bn * 256 + wnB + q * 16 + ccol;
            float bsv = bias[gn];
#pragma unroll
            for (int r = 0; r < 4; r++) {
                float v = acc[i][q][r] + bsv;
                size_t off = (gm + r) * (size_t)N + gn;
                if (EPI == 0) {
                    float g = 1.f / (1.f + __expf(-v));
                    ((float*)Coutv)[off] = g * extra[off];
                } else if (EPI == 1) {
                    ((unsigned short*)Coutv)[off] = f2bf(v > 0.f ? v : 0.f);
                } else {
                    ((float*)Coutv)[off] = v + extra[off];
                }
            }
        }
    }
}

// ---------- launch ----------
extern "C" void kernel_launch(void* const* d_in, const int* in_sizes, int n_in,
                              void* d_out, int out_size, void* d_ws, size_t ws_size,
                              hipStream_t stream) {
    const float* x   = (const float*)d_in[0];  // (B,T,C) fp32
    const float* n1w = (const float*)d_in[1];  // (C)
    const float* w1  = (const float*)d_in[2];  // (C,C)
    const float* b1  = (const float*)d_in[3];  // (C)
    const float* n2w = (const float*)d_in[4];  // (C)
    const float* w21 = (const float*)d_in[5];  // (C,E)
    const float* b21 = (const float*)d_in[6];  // (E)
    const float* w22 = (const float*)d_in[7];  // (E,C)
    const float* b22 = (const float*)d_in[8];  // (C)
    float* out = (float*)d_out;                // (B,T,C) fp32

    char* ws = (char*)d_ws;
    const size_t MB = 1024ull * 1024ull;
    unsigned short* state = (unsigned short*)(ws);            // 32MB bf16; reused as hnorm
    unsigned short* w1T   = (unsigned short*)(ws + 32 * MB);  // 2MB  (C x C) bf16
    unsigned short* w21T  = (unsigned short*)(ws + 34 * MB);  // 8MB  (E x C) bf16
    unsigned short* w22T  = (unsigned short*)(ws + 42 * MB);  // 8MB  (C x E) bf16
    float* P              = (float*)(ws + 50 * MB);           // 1MB
    float* rinv           = (float*)(ws + 51 * MB);           // 64KB
    unsigned short* h     = (unsigned short*)(ws + 52 * MB);  // up to 128MB bf16 (sliced)
    float* out1 = out;  // gate*x lives in d_out (fp32); G3 reads then overwrites per-element

    // pick M-slice size for the h buffer based on available workspace
    int slice_rows = Mdim;  // 16384 -> h=128MB (total 180MB); halve until it fits
    while (52 * MB + (size_t)slice_rows * Edim * 2 > ws_size && slice_rows > 1024)
        slice_rows >>= 1;

    // weights -> bf16 (N x K)
    transpose_f2b<<<dim3(Cdim / 32, Cdim / 32), 256, 0, stream>>>(w1, w1T, Cdim, Cdim);
    transpose_f2b<<<dim3(Edim / 32, Cdim / 32), 256, 0, stream>>>(w21, w21T, Cdim, Edim);
    transpose_f2b<<<dim3(Cdim / 32, Edim / 32), 256, 0, stream>>>(w22, w22T, Edim, Cdim);

    // rmsnorm1 scale factors
    rms_inv_kernel<<<Mdim, 256, 0, stream>>>(x, rinv);

    // chunked cumsum of x*rinv*n1w over T, with triangular scaler -> bf16 state
    chunk_sums<<<1024, 256, 0, stream>>>(x, rinv, n1w, P);
    chunk_scan<<<32, 256, 0, stream>>>(P);
    cumsum_state<<<1024, 256, 0, stream>>>(x, rinv, n1w, P, state);

    // G1: out1 = sigmoid(state @ w1 + b1) * x   (fp32 out into d_out)
    gemm8<0><<<dim3((Mdim / 256) * (Cdim / 256)), 512, 0, stream>>>(
        state, w1T, b1, x, out1, Cdim, Cdim);

    // rmsnorm2(out1) -> bf16 hnorm (reuse state buffer)
    rmsnorm_f2b<<<Mdim, 256, 0, stream>>>(out1, n2w, state);

    // G2/G3 sliced over M to bound the h buffer
    for (int m0 = 0; m0 < Mdim; m0 += slice_rows) {
        gemm8<1><<<dim3((slice_rows / 256) * (Edim / 256)), 512, 0, stream>>>(
            state + (size_t)m0 * Cdim, w21T, b21, nullptr, h, Edim, Cdim);
        gemm8<2><<<dim3((slice_rows / 256) * (Cdim / 256)), 512, 0, stream>>>(
            h, w22T, b22, out1 + (size_t)m0 * Cdim, out + (size_t)m0 * Cdim,
            Cdim, Edim);
    }
}

// Round 5
// 559.726 us; speedup vs baseline: 1.3877x; 1.0571x over previous
//
#include <hip/hip_runtime.h>

// ---------- bf16 helpers (raw ushort representation) ----------
__device__ __forceinline__ float bf2f(unsigned short u) {
    union { unsigned int i; float f; } v;
    v.i = ((unsigned int)u) << 16;
    return v.f;
}
__device__ __forceinline__ unsigned short f2bf(float f) {
    union { float f; unsigned int i; } v;
    v.f = f;
    unsigned int r = (v.i + 0x7fffu + ((v.i >> 16) & 1u)) >> 16;
    return (unsigned short)r;
}

typedef __attribute__((ext_vector_type(8))) short short8;
typedef __attribute__((ext_vector_type(4))) float floatx4;

#define GLOBAL_AS __attribute__((address_space(1)))
#define LDS_AS __attribute__((address_space(3)))

static constexpr int Bdim = 8;
static constexpr int Tdim = 2048;
static constexpr int Cdim = 1024;
static constexpr int Edim = 4096;
static constexpr int Mdim = Bdim * Tdim;  // 16384

// ---------- weight transpose + cast: src fp32 (K x N) -> dst bf16 (N x K) ----------
__global__ __launch_bounds__(256) void transpose_f2b(
    const float* __restrict__ src, unsigned short* __restrict__ dst, int K, int N) {
    __shared__ float tile[32][33];
    int n0 = blockIdx.x * 32;
    int k0 = blockIdx.y * 32;
    int tx = threadIdx.x & 31;
    int ty = threadIdx.x >> 5;  // 0..7
#pragma unroll
    for (int i = 0; i < 32; i += 8)
        tile[ty + i][tx] = src[(size_t)(k0 + ty + i) * N + n0 + tx];
    __syncthreads();
#pragma unroll
    for (int i = 0; i < 32; i += 8)
        dst[(size_t)(n0 + ty + i) * K + k0 + tx] = f2bf(tile[tx][ty + i]);
}

// ---------- rmsnorm1 inverse-RMS only: rinv[row] = rsqrt(mean(x^2)+eps) ----------
__global__ __launch_bounds__(256) void rms_inv_kernel(
    const float* __restrict__ x, float* __restrict__ rinv) {
    int row = blockIdx.x;
    int tid = threadIdx.x;
    float4 v = ((const float4*)(x + (size_t)row * Cdim))[tid];
    float s = v.x * v.x + v.y * v.y + v.z * v.z + v.w * v.w;
#pragma unroll
    for (int o = 32; o > 0; o >>= 1) s += __shfl_down(s, o, 64);
    __shared__ float ps[4];
    if ((tid & 63) == 0) ps[tid >> 6] = s;
    __syncthreads();
    if (tid == 0) {
        float tot = ps[0] + ps[1] + ps[2] + ps[3];
        rinv[row] = rsqrtf(tot * (1.0f / (float)Cdim) + 1e-6f);
    }
}

// ---------- cumsum phase A: per-chunk sums of y = x*rinv*w. 1024 blocks ----------
__global__ __launch_bounds__(256) void chunk_sums(
    const float* __restrict__ x, const float* __restrict__ rinv,
    const float* __restrict__ w, float* __restrict__ P) {
    int idx = blockIdx.x;
    int cb = idx & 3;
    int k = (idx >> 2) & 31;
    int b = idx >> 7;
    int c = cb * 256 + threadIdx.x;
    float wc = w[c];
    const float* base = x + ((size_t)b * Tdim + k * 64) * Cdim + c;
    const float* rbase = rinv + (size_t)b * Tdim + k * 64;
    float s = 0.f;
#pragma unroll 8
    for (int t = 0; t < 64; t++) s += base[(size_t)t * Cdim] * rbase[t];
    P[((size_t)b * 32 + k) * Cdim + c] = s * wc;
}

// ---------- cumsum phase B: exclusive scan of 32 chunk sums per (b,c) chain ----------
__global__ __launch_bounds__(256) void chunk_scan(float* __restrict__ P) {
    int g = blockIdx.x * 256 + threadIdx.x;  // 0..8191
    int b = g >> 10;
    int c = g & 1023;
    float* p = P + (size_t)b * 32 * Cdim + c;
    float run = 0.f;
#pragma unroll
    for (int k = 0; k < 32; k++) {
        float v = p[(size_t)k * Cdim];
        p[(size_t)k * Cdim] = run;
        run += v;
    }
}

// ---------- cumsum phase C: rescan, divide by triangular scaler, emit bf16 state ----------
__global__ __launch_bounds__(256) void cumsum_state(
    const float* __restrict__ x, const float* __restrict__ rinv,
    const float* __restrict__ w, const float* __restrict__ P,
    unsigned short* __restrict__ state) {
    int idx = blockIdx.x;
    int cb = idx & 3;
    int k = (idx >> 2) & 31;
    int b = idx >> 7;
    int c = cb * 256 + threadIdx.x;
    float wc = w[c];
    float acc = P[((size_t)b * 32 + k) * Cdim + c];
    const float* base = x + ((size_t)b * Tdim + k * 64) * Cdim + c;
    const float* rbase = rinv + (size_t)b * Tdim + k * 64;
    unsigned short* sbase = state + ((size_t)b * Tdim + k * 64) * Cdim + c;
#pragma unroll 4
    for (int t = 0; t < 64; t++) {
        acc += base[(size_t)t * Cdim] * rbase[t] * wc;
        int tt = k * 64 + t;
        float inv = 2.0f / ((float)(tt + 1) * (float)(tt + 2));
        sbase[(size_t)t * Cdim] = f2bf(acc * inv);
    }
}

// ---------- rmsnorm2: fp32 in -> bf16 out (GEMM A operand) ----------
__global__ __launch_bounds__(256) void rmsnorm_f2b(
    const float* __restrict__ x, const float* __restrict__ w,
    unsigned short* __restrict__ y) {
    int row = blockIdx.x;
    int tid = threadIdx.x;
    float4 v = ((const float4*)(x + (size_t)row * Cdim))[tid];
    float s = v.x * v.x + v.y * v.y + v.z * v.z + v.w * v.w;
#pragma unroll
    for (int o = 32; o > 0; o >>= 1) s += __shfl_down(s, o, 64);
    __shared__ float ps[4];
    if ((tid & 63) == 0) ps[tid >> 6] = s;
    __syncthreads();
    float tot = ps[0] + ps[1] + ps[2] + ps[3];
    float r = rsqrtf(tot * (1.0f / (float)Cdim) + 1e-6f);
    float4 w4 = ((const float4*)w)[tid];
    ushort4 o;
    o.x = f2bf(v.x * r * w4.x);
    o.y = f2bf(v.y * r * w4.y);
    o.z = f2bf(v.z * r * w4.z);
    o.w = f2bf(v.w * r * w4.w);
    ((ushort4*)(y + (size_t)row * Cdim))[tid] = o;
}

// ---------- bf16 MFMA GEMM: 256x256 tile, BK=64, 8-phase counted-vmcnt pipeline ----
// C(MxN) = A(MxK) @ BT^T. 512 threads = 8 waves (2M x 4N), per-wave output 128x64,
// acc[8][4]. 2 LDS buffers (buf t&1 holds K-tile t), 128 KiB total.
// r2 structure with the forced lgkmcnt drains REMOVED: each phase's ds_reads issue
// pre-barrier; after the barrier the compiler inserts fine-grained counted lgkmcnt
// before each dependent MFMA, so the tail of the read batch drains DURING the MFMA
// cluster instead of serializing ahead of it.
// Correctness without explicit lgkm:
//  * RAW on staged LDS: buf reads cannot hoist above the K-tile-boundary vmcnt gate
//    (asm "memory" clobber) that guarantees the DMA landed.
//  * WAR on re-staged LDS: last reader phase's MFMA has a register dep on the reads
//    -> they retire before that phase's closing barrier; the overwriting STAGE is
//    >=1 barrier later. gload_lds's LDS-write vs ds_read dependence is visible to
//    the compiler (no reorder).
// Stagger: ph0/1 stage A(2j+1); ph2/3 B(2j+2); ph4/5 A(2j+2)+B(2j+2)hi; ph6/7 B(2j+3).
// vmcnt gates only at ph3 (leave 2 newest in flight) and ph7 (leave 4 newest).
template <int EPI>
__global__ __launch_bounds__(512, 2) void gemm8(
    const unsigned short* __restrict__ A, const unsigned short* __restrict__ BT,
    const float* __restrict__ bias, const float* __restrict__ extra,
    void* __restrict__ Coutv, int N, int K) {
    __shared__ __attribute__((aligned(16))) unsigned short As[2][256 * 64];
    __shared__ __attribute__((aligned(16))) unsigned short Bs[2][256 * 64];

    int tid = threadIdx.x;
    int nbn = N >> 8;
    int id = blockIdx.x;
    int nwg = gridDim.x;
    // XCD-aware swizzle (all grids divisible by 8): contiguous chunk per XCD.
    if ((nwg & 7) == 0) id = (id & 7) * (nwg >> 3) + (id >> 3);
    int bn = id % nbn;
    int bm = id / nbn;

    int lane = tid & 63;
    int w = tid >> 6;     // 0..7
    int wm = w >> 2;      // 0..1 : rows wm*128 .. +127
    int wn = w & 3;       // 0..3 : cols wn*64 .. +63
    int lrow = lane & 15;
    int l4 = lane >> 4;   // 0..3
    int swz = lrow & 7;
    int wmB = wm * 128, wnB = wn * 64;

    const unsigned short* Abase = A + (size_t)bm * 256 * K;
    const unsigned short* Bbase = BT + (size_t)bn * 256 * K;

    // staging: unit u = 64 rows x 64 cols (8KB) = 1 global_load_lds per thread.
    // source column pre-swizzled so the linear LDS dest ends up XOR-swizzled.
    int sr = tid >> 3;                 // row within unit
    int col8 = (tid & 7) ^ (sr & 7);   // swizzled source 8-elem column block

#define STAGE_A(sb, u, k0)                                                               \
    __builtin_amdgcn_global_load_lds(                                                    \
        (const GLOBAL_AS void*)(Abase + (size_t)((u) * 64 + sr) * K + (k0) + col8 * 8),  \
        (LDS_AS void*)(As[sb] + (u) * 4096 + tid * 8), 16, 0, 0)
#define STAGE_B(sb, u, k0)                                                               \
    __builtin_amdgcn_global_load_lds(                                                    \
        (const GLOBAL_AS void*)(Bbase + (size_t)((u) * 64 + sr) * K + (k0) + col8 * 8),  \
        (LDS_AS void*)(Bs[sb] + (u) * 4096 + tid * 8), 16, 0, 0)

    // fragment reads (swizzled slot)
#define LDA(cb, i, ks)                                                                   \
    (*(const short8*)(As[cb] + (wmB + (i) * 16 + lrow) * 64 + ((((ks) * 4 + l4) ^ swz) << 3)))
#define LDB(cb, jj, ks)                                                                  \
    (*(const short8*)(Bs[cb] + (wnB + (jj) * 16 + lrow) * 64 + ((((ks) * 4 + l4) ^ swz) << 3)))

#define PH_IN                                                                            \
    do {                                                                                 \
        __builtin_amdgcn_s_barrier();                                                    \
        __builtin_amdgcn_s_setprio(1);                                                   \
    } while (0)
#define PH_OUT                                                                           \
    do {                                                                                 \
        __builtin_amdgcn_s_setprio(0);                                                   \
        __builtin_amdgcn_s_barrier();                                                    \
    } while (0)

    floatx4 acc[8][4] = {};
    int nt = K >> 6;       // K-tiles (even: K is a multiple of 128 here)
    int nIter = nt >> 1;

    // prologue: A(0), B(0) fully; B(1) fully. vmcnt(4): tile 0 landed, B(1) in flight.
    STAGE_A(0, 0, 0); STAGE_A(0, 1, 0); STAGE_A(0, 2, 0); STAGE_A(0, 3, 0);
    STAGE_B(0, 0, 0); STAGE_B(0, 1, 0); STAGE_B(0, 2, 0); STAGE_B(0, 3, 0);
    STAGE_B(1, 0, 64); STAGE_B(1, 1, 64); STAGE_B(1, 2, 64); STAGE_B(1, 3, 64);
    asm volatile("s_waitcnt vmcnt(4)" ::: "memory");
    __builtin_amdgcn_s_barrier();

    for (int j = 0; j < nIter; ++j) {
        int k1 = (2 * j + 1) << 6;
        int k2 = (2 * j + 2) << 6;
        int k3 = (2 * j + 3) << 6;
        bool nl = (j + 1 < nIter);

        short8 av[4], b0[4], b1[4];

        // ---- ph0: tile 2j, wave rows 0-63, ks=0 ----
#pragma unroll
        for (int i = 0; i < 4; i++) av[i] = LDA(0, i, 0);
#pragma unroll
        for (int i = 0; i < 4; i++) b0[i] = LDB(0, i, 0);
        STAGE_A(1, 0, k1); STAGE_A(1, 1, k1);
        PH_IN;
#pragma unroll
        for (int i = 0; i < 4; i++)
#pragma unroll
            for (int q = 0; q < 4; q++)
                acc[i][q] = __builtin_amdgcn_mfma_f32_16x16x32_bf16(av[i], b0[q], acc[i][q], 0, 0, 0);
        PH_OUT;

        // ---- ph1: tile 2j, wave rows 0-63, ks=1 ----
#pragma unroll
        for (int i = 0; i < 4; i++) av[i] = LDA(0, i, 1);
#pragma unroll
        for (int i = 0; i < 4; i++) b1[i] = LDB(0, i, 1);
        STAGE_A(1, 2, k1); STAGE_A(1, 3, k1);
        PH_IN;
#pragma unroll
        for (int i = 0; i < 4; i++)
#pragma unroll
            for (int q = 0; q < 4; q++)
                acc[i][q] = __builtin_amdgcn_mfma_f32_16x16x32_bf16(av[i], b1[q], acc[i][q], 0, 0, 0);
        PH_OUT;

        // ---- ph2: tile 2j, wave rows 64-127, ks=0 (b0 reused) ----
#pragma unroll
        for (int i = 0; i < 4; i++) av[i] = LDA(0, 4 + i, 0);
        if (nl) { STAGE_B(0, 0, k2); STAGE_B(0, 1, k2); }
        PH_IN;
#pragma unroll
        for (int i = 0; i < 4; i++)
#pragma unroll
            for (int q = 0; q < 4; q++)
                acc[4 + i][q] = __builtin_amdgcn_mfma_f32_16x16x32_bf16(av[i], b0[q], acc[4 + i][q], 0, 0, 0);
        PH_OUT;

        // ---- ph3: tile 2j, wave rows 64-127, ks=1 (b1 reused); vmcnt gate ----
#pragma unroll
        for (int i = 0; i < 4; i++) av[i] = LDA(0, 4 + i, 1);
        if (nl) { STAGE_B(0, 2, k2); STAGE_B(0, 3, k2); }
        if (nl) asm volatile("s_waitcnt vmcnt(2)" ::: "memory");
        else    asm volatile("s_waitcnt vmcnt(0)" ::: "memory");
        PH_IN;
#pragma unroll
        for (int i = 0; i < 4; i++)
#pragma unroll
            for (int q = 0; q < 4; q++)
                acc[4 + i][q] = __builtin_amdgcn_mfma_f32_16x16x32_bf16(av[i], b1[q], acc[4 + i][q], 0, 0, 0);
        PH_OUT;

        // ---- ph4: tile 2j+1, wave rows 0-63, ks=0 ----
#pragma unroll
        for (int i = 0; i < 4; i++) av[i] = LDA(1, i, 0);
#pragma unroll
        for (int i = 0; i < 4; i++) b0[i] = LDB(1, i, 0);
        if (nl) { STAGE_A(0, 0, k2); STAGE_A(0, 1, k2); }
        PH_IN;
#pragma unroll
        for (int i = 0; i < 4; i++)
#pragma unroll
            for (int q = 0; q < 4; q++)
                acc[i][q] = __builtin_amdgcn_mfma_f32_16x16x32_bf16(av[i], b0[q], acc[i][q], 0, 0, 0);
        PH_OUT;

        // ---- ph5: tile 2j+1, wave rows 0-63, ks=1 ----
#pragma unroll
        for (int i = 0; i < 4; i++) av[i] = LDA(1, i, 1);
#pragma unroll
        for (int i = 0; i < 4; i++) b1[i] = LDB(1, i, 1);
        if (nl) { STAGE_A(0, 2, k2); STAGE_A(0, 3, k2); }
        PH_IN;
#pragma unroll
        for (int i = 0; i < 4; i++)
#pragma unroll
            for (int q = 0; q < 4; q++)
                acc[i][q] = __builtin_amdgcn_mfma_f32_16x16x32_bf16(av[i], b1[q], acc[i][q], 0, 0, 0);
        PH_OUT;

        // ---- ph6: tile 2j+1, wave rows 64-127, ks=0 ----
#pragma unroll
        for (int i = 0; i < 4; i++) av[i] = LDA(1, 4 + i, 0);
        if (nl) { STAGE_B(1, 0, k3); STAGE_B(1, 1, k3); }
        PH_IN;
#pragma unroll
        for (int i = 0; i < 4; i++)
#pragma unroll
            for (int q = 0; q < 4; q++)
                acc[4 + i][q] = __builtin_amdgcn_mfma_f32_16x16x32_bf16(av[i], b0[q], acc[4 + i][q], 0, 0, 0);
        PH_OUT;

        // ---- ph7: tile 2j+1, wave rows 64-127, ks=1; vmcnt gate ----
#pragma unroll
        for (int i = 0; i < 4; i++) av[i] = LDA(1, 4 + i, 1);
        if (nl) { STAGE_B(1, 2, k3); STAGE_B(1, 3, k3); }
        if (nl) asm volatile("s_waitcnt vmcnt(4)" ::: "memory");
        PH_IN;
#pragma unroll
        for (int i = 0; i < 4; i++)
#pragma unroll
            for (int q = 0; q < 4; q++)
                acc[4 + i][q] = __builtin_amdgcn_mfma_f32_16x16x32_bf16(av[i], b1[q], acc[4 + i][q], 0, 0, 0);
        PH_OUT;
    }
#undef STAGE_A
#undef STAGE_B
#undef LDA
#undef LDB
#undef PH_IN
#undef PH_OUT

    // final drain: last iteration staged nothing new; all reads already consumed.
    asm volatile("s_waitcnt vmcnt(0)" ::: "memory");

    // epilogue: C/D layout col=lane&15, row=(lane>>4)*4+reg
    int crow = l4 << 2;
    int ccol = lane & 15;
#pragma unroll
    for (int i = 0; i < 8; i++) {
#pragma unroll
        for (int q = 0; q < 4; q++) {
            size_t gm = (size_t)bm * 256 + wmB + i * 16 + crow;
            size_t gn = (size_t)bn * 256 + wnB + q * 16 + ccol;
            float bsv = bias[gn];
#pragma unroll
            for (int r = 0; r < 4; r++) {
                float v = acc[i][q][r] + bsv;
                size_t off = (gm + r) * (size_t)N + gn;
                if (EPI == 0) {
                    float g = 1.f / (1.f + __expf(-v));
                    ((float*)Coutv)[off] = g * extra[off];
                } else if (EPI == 1) {
                    ((unsigned short*)Coutv)[off] = f2bf(v > 0.f ? v : 0.f);
                } else {
                    ((float*)Coutv)[off] = v + extra[off];
                }
            }
        }
    }
}

// ---------- launch ----------
extern "C" void kernel_launch(void* const* d_in, const int* in_sizes, int n_in,
                              void* d_out, int out_size, void* d_ws, size_t ws_size,
                              hipStream_t stream) {
    const float* x   = (const float*)d_in[0];  // (B,T,C) fp32
    const float* n1w = (const float*)d_in[1];  // (C)
    const float* w1  = (const float*)d_in[2];  // (C,C)
    const float* b1  = (const float*)d_in[3];  // (C)
    const float* n2w = (const float*)d_in[4];  // (C)
    const float* w21 = (const float*)d_in[5];  // (C,E)
    const float* b21 = (const float*)d_in[6];  // (E)
    const float* w22 = (const float*)d_in[7];  // (E,C)
    const float* b22 = (const float*)d_in[8];  // (C)
    float* out = (float*)d_out;                // (B,T,C) fp32

    char* ws = (char*)d_ws;
    const size_t MB = 1024ull * 1024ull;
    unsigned short* state = (unsigned short*)(ws);            // 32MB bf16; reused as hnorm
    unsigned short* w1T   = (unsigned short*)(ws + 32 * MB);  // 2MB  (C x C) bf16
    unsigned short* w21T  = (unsigned short*)(ws + 34 * MB);  // 8MB  (E x C) bf16
    unsigned short* w22T  = (unsigned short*)(ws + 42 * MB);  // 8MB  (C x E) bf16
    float* P              = (float*)(ws + 50 * MB);           // 1MB
    float* rinv           = (float*)(ws + 51 * MB);           // 64KB
    unsigned short* h     = (unsigned short*)(ws + 52 * MB);  // up to 128MB bf16 (sliced)
    float* out1 = out;  // gate*x lives in d_out (fp32); G3 reads then overwrites per-element

    // pick M-slice size for the h buffer based on available workspace
    int slice_rows = Mdim;  // 16384 -> h=128MB (total 180MB); halve until it fits
    while (52 * MB + (size_t)slice_rows * Edim * 2 > ws_size && slice_rows > 1024)
        slice_rows >>= 1;

    // weights -> bf16 (N x K)
    transpose_f2b<<<dim3(Cdim / 32, Cdim / 32), 256, 0, stream>>>(w1, w1T, Cdim, Cdim);
    transpose_f2b<<<dim3(Edim / 32, Cdim / 32), 256, 0, stream>>>(w21, w21T, Cdim, Edim);
    transpose_f2b<<<dim3(Cdim / 32, Edim / 32), 256, 0, stream>>>(w22, w22T, Edim, Cdim);

    // rmsnorm1 scale factors
    rms_inv_kernel<<<Mdim, 256, 0, stream>>>(x, rinv);

    // chunked cumsum of x*rinv*n1w over T, with triangular scaler -> bf16 state
    chunk_sums<<<1024, 256, 0, stream>>>(x, rinv, n1w, P);
    chunk_scan<<<32, 256, 0, stream>>>(P);
    cumsum_state<<<1024, 256, 0, stream>>>(x, rinv, n1w, P, state);

    // G1: out1 = sigmoid(state @ w1 + b1) * x   (fp32 out into d_out)
    gemm8<0><<<dim3((Mdim / 256) * (Cdim / 256)), 512, 0, stream>>>(
        state, w1T, b1, x, out1, Cdim, Cdim);

    // rmsnorm2(out1) -> bf16 hnorm (reuse state buffer)
    rmsnorm_f2b<<<Mdim, 256, 0, stream>>>(out1, n2w, state);

    // G2/G3 sliced over M to bound the h buffer
    for (int m0 = 0; m0 < Mdim; m0 += slice_rows) {
        gemm8<1><<<dim3((slice_rows / 256) * (Edim / 256)), 512, 0, stream>>>(
            state + (size_t)m0 * Cdim, w21T, b21, nullptr, h, Edim, Cdim);
        gemm8<2><<<dim3((slice_rows / 256) * (Cdim / 256)), 512, 0, stream>>>(
            h, w22T, b22, out1 + (size_t)m0 * Cdim, out + (size_t)m0 * Cdim,
            Cdim, Edim);
    }
}